// Round 8
// baseline (2020.605 us; speedup 1.0000x reference)
//
#include <hip/hip_runtime.h>
#include <hip/hip_bf16.h>
#include <stdint.h>

#define LNUM 6
#define BB 8
#define TT 1024
#define CC 768
#define HH 12
#define HDIM 64
#define DFF 3072
#define VV 512
#define MM (BB*TT)
#define QKREG ((size_t)BB*HH*TT*64)

typedef __bf16 bf16x8 __attribute__((ext_vector_type(8)));
typedef float f32x4 __attribute__((ext_vector_type(4)));

__device__ __forceinline__ uint16_t f2b(float f) {
  uint32_t u = __float_as_uint(f);
  u += 0x7FFFu + ((u >> 16) & 1u);
  return (uint16_t)(u >> 16);
}

__device__ __forceinline__ void gld16(const uint16_t* g, uint16_t* l) {
  __builtin_amdgcn_global_load_lds(
      (const __attribute__((address_space(1))) uint32_t*)g,
      (__attribute__((address_space(3))) uint32_t*)l, 16, 0, 0);
}

__device__ __forceinline__ f32x4 mfma16(bf16x8 a, bf16x8 b, f32x4 c) {
  return __builtin_amdgcn_mfma_f32_16x16x32_bf16(a, b, c, 0, 0, 0);
}

// ---------------- convert f32 -> bf16 ----------------
__global__ __launch_bounds__(256) void cvt4_k(const float* __restrict__ in,
                                              uint16_t* __restrict__ out, int n4) {
  const int gid = blockIdx.x * 256 + threadIdx.x;
  if (gid >= n4) return;
  const float4 v = ((const float4*)in)[gid];
  ushort4 w; w.x = f2b(v.x); w.y = f2b(v.y); w.z = f2b(v.z); w.w = f2b(v.w);
  ((ushort4*)out)[gid] = w;
}

// ---------------- embedding ----------------
__global__ __launch_bounds__(256) void embed_k(const int* __restrict__ idx,
                                               const float* __restrict__ tok,
                                               const float* __restrict__ pos,
                                               float* __restrict__ x) {
  const int gid = blockIdx.x * 256 + threadIdx.x;
  const int row = gid / (CC / 4), c4 = gid % (CC / 4);
  const int t = row & (TT - 1);
  const int tkn = idx[row];
  const float4 a = ((const float4*)(tok + (size_t)tkn * CC))[c4];
  const float4 q = ((const float4*)(pos + (size_t)t * CC))[c4];
  ((float4*)(x + (size_t)row * CC))[c4] =
      make_float4(a.x + q.x, a.y + q.y, a.z + q.z, a.w + q.w);
}

// ---------------- layernorm: fp32 in -> bf16 out ----------------
__global__ __launch_bounds__(256) void ln_k(const float* __restrict__ x,
                                            const float* __restrict__ gamma,
                                            const float* __restrict__ beta,
                                            uint16_t* __restrict__ o) {
  const int lane = threadIdx.x & 63, wid = threadIdx.x >> 6;
  const int row = blockIdx.x * 4 + wid;
  const float4* xr = (const float4*)(x + (size_t)row * CC);
  float4 v[3]; float s = 0.f, sq = 0.f;
#pragma unroll
  for (int i = 0; i < 3; ++i) {
    v[i] = xr[lane + i * 64];
    s += v[i].x + v[i].y + v[i].z + v[i].w;
    sq += v[i].x * v[i].x + v[i].y * v[i].y + v[i].z * v[i].z + v[i].w * v[i].w;
  }
#pragma unroll
  for (int m = 1; m < 64; m <<= 1) { s += __shfl_xor(s, m, 64); sq += __shfl_xor(sq, m, 64); }
  const float mu = s * (1.f / 768.f);
  const float rstd = rsqrtf(sq * (1.f / 768.f) - mu * mu + 1e-5f);
  ushort4* orow = (ushort4*)(o + (size_t)row * CC);
#pragma unroll
  for (int i = 0; i < 3; ++i) {
    const int c4 = lane + i * 64;
    const float4 gg = ((const float4*)gamma)[c4];
    const float4 bb = ((const float4*)beta)[c4];
    ushort4 w;
    w.x = f2b((v[i].x - mu) * rstd * gg.x + bb.x);
    w.y = f2b((v[i].y - mu) * rstd * gg.y + bb.y);
    w.z = f2b((v[i].z - mu) * rstd * gg.z + bb.z);
    w.w = f2b((v[i].w - mu) * rstd * gg.w + bb.w);
    orow[c4] = w;
  }
}

// ------- layernorm + partial-sum reduce: x += p0+p1; o = LN(x)  -------
__global__ __launch_bounds__(256) void lnr_k(float* __restrict__ x,
                                             const float* __restrict__ p0,
                                             const float* __restrict__ p1,
                                             const float* __restrict__ gamma,
                                             const float* __restrict__ beta,
                                             uint16_t* __restrict__ o) {
  const int lane = threadIdx.x & 63, wid = threadIdx.x >> 6;
  const int row = blockIdx.x * 4 + wid;
  float4* xr = (float4*)(x + (size_t)row * CC);
  const float4* pr0 = (const float4*)(p0 + (size_t)row * CC);
  const float4* pr1 = (const float4*)(p1 + (size_t)row * CC);
  float4 v[3]; float s = 0.f, sq = 0.f;
#pragma unroll
  for (int i = 0; i < 3; ++i) {
    const int c4 = lane + i * 64;
    float4 a = xr[c4];
    const float4 q0 = pr0[c4];
    const float4 q1 = pr1[c4];
    a.x += q0.x + q1.x; a.y += q0.y + q1.y;
    a.z += q0.z + q1.z; a.w += q0.w + q1.w;
    xr[c4] = a;
    v[i] = a;
    s += a.x + a.y + a.z + a.w;
    sq += a.x * a.x + a.y * a.y + a.z * a.z + a.w * a.w;
  }
#pragma unroll
  for (int m = 1; m < 64; m <<= 1) { s += __shfl_xor(s, m, 64); sq += __shfl_xor(sq, m, 64); }
  const float mu = s * (1.f / 768.f);
  const float rstd = rsqrtf(sq * (1.f / 768.f) - mu * mu + 1e-5f);
  ushort4* orow = (ushort4*)(o + (size_t)row * CC);
#pragma unroll
  for (int i = 0; i < 3; ++i) {
    const int c4 = lane + i * 64;
    const float4 gg = ((const float4*)gamma)[c4];
    const float4 bb = ((const float4*)beta)[c4];
    ushort4 w;
    w.x = f2b((v[i].x - mu) * rstd * gg.x + bb.x);
    w.y = f2b((v[i].y - mu) * rstd * gg.y + bb.y);
    w.z = f2b((v[i].z - mu) * rstd * gg.z + bb.z);
    w.w = f2b((v[i].w - mu) * rstd * gg.w + bb.w);
    orow[c4] = w;
  }
}

// ---------------- transpose+convert weights ----------------
__global__ __launch_bounds__(256) void tconv_k(const float* __restrict__ in,
                                               uint16_t* __restrict__ out, int K, int N) {
  __shared__ float tile[32][33];
  const int kt = blockIdx.x * 32, nt = blockIdx.y * 32;
  const int tx = threadIdx.x & 31, ty = threadIdx.x >> 5;
#pragma unroll
  for (int i = 0; i < 32; i += 8)
    tile[ty + i][tx] = in[(size_t)(kt + ty + i) * N + nt + tx];
  __syncthreads();
#pragma unroll
  for (int i = 0; i < 32; i += 8)
    out[(size_t)(nt + ty + i) * K + kt + tx] = f2b(tile[tx][ty + i]);
}

// ---------------- old 128x128 GEMM (logits + fallback) ----------------
// EPI: 1 = f32 store; 3 = resid +=; 4 = resid += (+bias)
template <int EPI>
__global__ __launch_bounds__(256) void gemm_k(const uint16_t* __restrict__ A,
                                              const uint16_t* __restrict__ Bt,
                                              int N, int K,
                                              const float* __restrict__ bias,
                                              float* __restrict__ resid,
                                              uint16_t* __restrict__ outb,
                                              float* __restrict__ outf) {
  __shared__ __align__(16) uint16_t As[128 * 32];
  __shared__ __align__(16) uint16_t Bs[128 * 32];
  const int lane = threadIdx.x & 63, wid = threadIdx.x >> 6;
  const int wm = wid >> 1, wn = wid & 1;
  const int bm = blockIdx.x * 128, bn = blockIdx.y * 128;
  const int rsub = lane >> 2, csub = (lane & 3) * 8;
  f32x4 acc[4][4] = {};
  for (int k0 = 0; k0 < K; k0 += 32) {
#pragma unroll
    for (int q = 0; q < 2; ++q) {
      const int ch = wid * 2 + q;
      gld16(A + (size_t)(bm + ch * 16 + rsub) * K + k0 + csub, &As[ch * 512]);
      gld16(Bt + (size_t)(bn + ch * 16 + rsub) * K + k0 + csub, &Bs[ch * 512]);
    }
    __syncthreads();
    bf16x8 a[4], b[4];
#pragma unroll
    for (int i = 0; i < 4; ++i) {
      a[i] = *(const bf16x8*)&As[(wm * 64 + i * 16 + (lane & 15)) * 32 + (lane >> 4) * 8];
      b[i] = *(const bf16x8*)&Bs[(wn * 64 + i * 16 + (lane & 15)) * 32 + (lane >> 4) * 8];
    }
#pragma unroll
    for (int i = 0; i < 4; ++i)
#pragma unroll
      for (int j = 0; j < 4; ++j)
        acc[i][j] = mfma16(a[i], b[j], acc[i][j]);
    __syncthreads();
  }
#pragma unroll
  for (int i = 0; i < 4; ++i) {
    const int m0 = bm + wm * 64 + i * 16 + ((lane >> 4) << 2);
#pragma unroll
    for (int j = 0; j < 4; ++j) {
      const int n = bn + wn * 64 + j * 16 + (lane & 15);
#pragma unroll
      for (int r = 0; r < 4; ++r) {
        const size_t o = (size_t)(m0 + r) * N + n;
        const float v = acc[i][j][r];
        if constexpr (EPI == 1) {
          outf[o] = v;
        } else if constexpr (EPI == 3) {
          resid[o] += v;
        } else if constexpr (EPI == 4) {
          resid[o] += v + bias[n];
        }
      }
    }
  }
}

// ========= 256x256 8-phase GEMM (m201-style), BK=64, 8 waves 2Mx4N =========
// LDS 128KB: [2 dbuf][2 half][128x64] per operand. Wave = 128x64 output.
// Per K-tile: 4 phases x 16 MFMA; reads 12/4/8/0; staging for tile t+1
// front-loaded into P1-P2 (newest load >= 2 phases before boundary vmcnt(0)).
// Raw s_barrier only. Swizzle: slot' = slot ^ (row&7), same involution on
// pre-swizzled global source and read side; gld16 dest stays linear.
// EPI: 2 = bias+GELU bf16; 3 = resid +=; 5 = qkv split; 7 = f32 partials
#define STGU(ARR, GB, nb, h, T)                                               \
  do {                                                                        \
    gld16((GB) + (size_t)(h) * 128 * K + (size_t)(T) * 64,                    \
          &ARR[nb][h][tid * 8]);                                              \
    gld16((GB) + (size_t)(h) * 128 * K + (size_t)64 * K + (size_t)(T) * 64,   \
          &ARR[nb][h][4096 + tid * 8]);                                       \
  } while (0)

template <int EPI>
__global__ __launch_bounds__(512, 2) void g256_k(const uint16_t* __restrict__ A,
                                                 const uint16_t* __restrict__ Bt,
                                                 int N, int K, int nbn, int kparts,
                                                 const float* __restrict__ bias,
                                                 float* __restrict__ resid,
                                                 uint16_t* __restrict__ outb,
                                                 float* __restrict__ outf) {
  __shared__ uint16_t Ah[2][2][8192];
  __shared__ uint16_t Bh[2][2][8192];
  const int tid = threadIdx.x, lane = tid & 63, wid = tid >> 6;
  const int l15 = lane & 15, lhi = lane >> 4;
  const int wm = wid >> 2, wn = wid & 3;
  int id = blockIdx.x;
  const int nwg = gridDim.x;
  id = (id & 7) * (nwg >> 3) + (id >> 3);  // XCD swizzle; all grids %8==0
  const int nbmn = nwg / kparts;
  const int kp = id / nbmn;
  const int rid = id - kp * nbmn;
  const int im = rid / nbn, in = rid - im * nbn;
  const int bm = im * 256, bn = in * 256;
  const int Ksub = K / kparts, k0 = kp * Ksub, nkt = Ksub >> 6;
  // staging: unit u = q*512+tid -> LDS byte u*16 (linear); row=u>>3, slot=u&7;
  // content must be global slot (u&7)^(row&7). q=1 adds 64 rows (same xor).
  const int r0 = tid >> 3;
  const int s0 = (tid & 7) ^ (r0 & 7);
  const uint16_t* gAb = A + (size_t)(bm + r0) * K + k0 + s0 * 8;
  const uint16_t* gBb = Bt + (size_t)(bn + r0) * K + k0 + s0 * 8;
  // read-side swizzled column bytes (row&7 == l15&7 for all fragments)
  const int swz0 = ((0 * 4 + lhi) ^ (l15 & 7)) << 4;
  const int swz1 = ((1 * 4 + lhi) ^ (l15 & 7)) << 4;

  f32x4 acc[8][4] = {};
  // prologue: stage K-tile 0 into dbuf 0
  STGU(Ah, gAb, 0, 0, 0);
  STGU(Ah, gAb, 0, 1, 0);
  STGU(Bh, gBb, 0, 0, 0);
  STGU(Bh, gBb, 0, 1, 0);
  asm volatile("s_waitcnt vmcnt(0)" ::: "memory");
  asm volatile("s_barrier" ::: "memory");

  for (int t = 0; t < nkt; ++t) {
    const int cur = t & 1, nb = cur ^ 1;
    const bool st = (t + 1) < nkt;
    const char* Ab = (const char*)Ah[cur][wm];
    const char* Bb = (const char*)Bh[cur][wn >> 1];
    const int brow = (wn & 1) * 64;
    bf16x8 a[4][2], b01[2][2], b23[2][2];
    // ---- P1: read A m0-3 (8) + B n0-1 (4); stage A0,B0 of t+1 ----
#pragma unroll
    for (int mm = 0; mm < 4; ++mm) {
      a[mm][0] = *(const bf16x8*)(Ab + (mm * 16 + l15) * 128 + swz0);
      a[mm][1] = *(const bf16x8*)(Ab + (mm * 16 + l15) * 128 + swz1);
    }
#pragma unroll
    for (int nn = 0; nn < 2; ++nn) {
      b01[nn][0] = *(const bf16x8*)(Bb + (brow + nn * 16 + l15) * 128 + swz0);
      b01[nn][1] = *(const bf16x8*)(Bb + (brow + nn * 16 + l15) * 128 + swz1);
    }
    if (st) { STGU(Ah, gAb, nb, 0, t + 1); STGU(Bh, gBb, nb, 0, t + 1); }
    asm volatile("s_waitcnt lgkmcnt(8)" ::: "memory");
    asm volatile("s_barrier" ::: "memory");
    asm volatile("s_waitcnt lgkmcnt(0)" ::: "memory");
    __builtin_amdgcn_sched_barrier(0);
    __builtin_amdgcn_s_setprio(1);
#pragma unroll
    for (int ks = 0; ks < 2; ++ks)
#pragma unroll
      for (int mm = 0; mm < 4; ++mm)
#pragma unroll
        for (int nn = 0; nn < 2; ++nn)
          acc[mm][nn] = mfma16(a[mm][ks], b01[nn][ks], acc[mm][nn]);
    __builtin_amdgcn_s_setprio(0);
    asm volatile("s_barrier" ::: "memory");
    // ---- P2: read B n2-3 (4); stage A1,B1 of t+1 ----
#pragma unroll
    for (int nn = 0; nn < 2; ++nn) {
      b23[nn][0] = *(const bf16x8*)(Bb + (brow + (nn + 2) * 16 + l15) * 128 + swz0);
      b23[nn][1] = *(const bf16x8*)(Bb + (brow + (nn + 2) * 16 + l15) * 128 + swz1);
    }
    if (st) { STGU(Ah, gAb, nb, 1, t + 1); STGU(Bh, gBb, nb, 1, t + 1); }
    asm volatile("s_barrier" ::: "memory");
    asm volatile("s_waitcnt lgkmcnt(0)" ::: "memory");
    __builtin_amdgcn_sched_barrier(0);
    __builtin_amdgcn_s_setprio(1);
#pragma unroll
    for (int ks = 0; ks < 2; ++ks)
#pragma unroll
      for (int mm = 0; mm < 4; ++mm)
#pragma unroll
        for (int nn = 0; nn < 2; ++nn)
          acc[mm][nn + 2] = mfma16(a[mm][ks], b23[nn][ks], acc[mm][nn + 2]);
    __builtin_amdgcn_s_setprio(0);
    asm volatile("s_barrier" ::: "memory");
    // ---- P3: read A m4-7 (8) ----
#pragma unroll
    for (int mm = 0; mm < 4; ++mm) {
      a[mm][0] = *(const bf16x8*)(Ab + ((mm + 4) * 16 + l15) * 128 + swz0);
      a[mm][1] = *(const bf16x8*)(Ab + ((mm + 4) * 16 + l15) * 128 + swz1);
    }
    asm volatile("s_barrier" ::: "memory");
    asm volatile("s_waitcnt lgkmcnt(0)" ::: "memory");
    __builtin_amdgcn_sched_barrier(0);
    __builtin_amdgcn_s_setprio(1);
#pragma unroll
    for (int ks = 0; ks < 2; ++ks)
#pragma unroll
      for (int mm = 0; mm < 4; ++mm)
#pragma unroll
        for (int nn = 0; nn < 2; ++nn)
          acc[mm + 4][nn + 2] = mfma16(a[mm][ks], b23[nn][ks], acc[mm + 4][nn + 2]);
    __builtin_amdgcn_s_setprio(0);
    asm volatile("s_barrier" ::: "memory");
    // ---- P4: pure-register MFMA (a hi-half x b01) + boundary ----
    __builtin_amdgcn_s_setprio(1);
#pragma unroll
    for (int ks = 0; ks < 2; ++ks)
#pragma unroll
      for (int mm = 0; mm < 4; ++mm)
#pragma unroll
        for (int nn = 0; nn < 2; ++nn)
          acc[mm + 4][nn] = mfma16(a[mm][ks], b01[nn][ks], acc[mm + 4][nn]);
    __builtin_amdgcn_s_setprio(0);
    if (st) asm volatile("s_waitcnt vmcnt(0)" ::: "memory");
    asm volatile("s_barrier" ::: "memory");
  }
  // ---- epilogue ----
#pragma unroll
  for (int mf = 0; mf < 8; ++mf) {
    const int m0 = bm + wm * 128 + mf * 16 + (lhi << 2);
#pragma unroll
    for (int nf = 0; nf < 4; ++nf) {
      const int col = bn + wn * 64 + nf * 16 + l15;
      if constexpr (EPI == 2) {
        const float bb = bias[col];
#pragma unroll
        for (int rr = 0; rr < 4; ++rr) {
          float tt = acc[mf][nf][rr] + bb;
          tt = 0.5f * tt * (1.0f + erff(tt * 0.70710678118654752f));
          outb[(size_t)(m0 + rr) * N + col] = f2b(tt);
        }
      } else if constexpr (EPI == 3) {
#pragma unroll
        for (int rr = 0; rr < 4; ++rr)
          resid[(size_t)(m0 + rr) * N + col] += acc[mf][nf][rr];
      } else if constexpr (EPI == 5) {
        const int sec = col / CC;
        const int rn = col - sec * CC;
        const int hh = rn >> 6, d = rn & 63;
        const int b = m0 >> 10, t0 = m0 & 1023;
        if (sec == 2) {
          ushort4 w;
          w.x = f2b(acc[mf][nf][0]); w.y = f2b(acc[mf][nf][1]);
          w.z = f2b(acc[mf][nf][2]); w.w = f2b(acc[mf][nf][3]);
          *(ushort4*)(outb + 2 * QKREG + ((size_t)(b * HH + hh) * 64 + d) * TT + t0) = w;
        } else {
          uint16_t* dst = outb + (size_t)sec * QKREG + ((size_t)(b * HH + hh) * TT + t0) * 64 + d;
#pragma unroll
          for (int rr = 0; rr < 4; ++rr) dst[(size_t)rr * 64] = f2b(acc[mf][nf][rr]);
        }
      } else {  // EPI 7: f32 partial store (+bias on kp==0)
        float* pdst = outf + (size_t)kp * ((size_t)MM * CC);
        const float bb = (kp == 0 && bias) ? bias[col] : 0.f;
#pragma unroll
        for (int rr = 0; rr < 4; ++rr)
          pdst[(size_t)(m0 + rr) * N + col] = acc[mf][nf][rr] + bb;
      }
    }
  }
}

// ---------------- fused causal flash attention ----------------
__global__ __launch_bounds__(256) void attn_k(const uint16_t* __restrict__ qkvh,
                                              uint16_t* __restrict__ ao) {
  __shared__ __align__(16) uint16_t Ks[64 * 64], Vs[64 * 64];
  __shared__ __align__(16) uint16_t Ps[4][16 * 64];
  const int tid = threadIdx.x, lane = tid & 63, wid = tid >> 6;
  const int qt = (TT / 64 - 1) - blockIdx.x / (BB * HH);
  const int bh = blockIdx.x % (BB * HH);
  const uint16_t* qb = qkvh + (size_t)bh * (TT * 64);
  const uint16_t* kb = qkvh + QKREG + (size_t)bh * (TT * 64);
  const uint16_t* vb = qkvh + 2 * QKREG + (size_t)bh * ((size_t)64 * TT);
  const int l15 = lane & 15, lhi = lane >> 4;
  bf16x8 qf[2];
  {
    const uint16_t* qr = qb + (size_t)(qt * 64 + wid * 16 + l15) * 64 + lhi * 8;
    qf[0] = *(const bf16x8*)qr;
    qf[1] = *(const bf16x8*)(qr + 32);
  }
  const int c0 = tid, c1 = tid + 256;
  const int r0 = c0 >> 3, r1 = c1 >> 3;
  const int cb0 = (c0 & 7) * 16, cb1 = (c1 & 7) * 16;
  const int ph0 = r0 * 128 + (cb0 ^ ((r0 & 7) << 4));
  const int ph1 = r1 * 128 + (cb1 ^ ((r1 & 7) << 4));

  uint4 kr0, kr1, vr0, vr1;
  kr0 = *(const uint4*)(kb + (size_t)r0 * 64 + cb0 / 2);
  kr1 = *(const uint4*)(kb + (size_t)r1 * 64 + cb1 / 2);
  vr0 = *(const uint4*)(vb + (size_t)r0 * TT + cb0 / 2);
  vr1 = *(const uint4*)(vb + (size_t)r1 * TT + cb1 / 2);
  *(uint4*)((char*)Ks + ph0) = kr0;
  *(uint4*)((char*)Ks + ph1) = kr1;
  *(uint4*)((char*)Vs + ph0) = vr0;
  *(uint4*)((char*)Vs + ph1) = vr1;
  __syncthreads();

  f32x4 oacc[4] = {};
  float mrun[4] = {-INFINITY, -INFINITY, -INFINITY, -INFINITY};
  float lrun[4] = {0.f, 0.f, 0.f, 0.f};
  char* pb = (char*)Ps[wid];

  for (int j = 0; j <= qt; ++j) {
    const bool more = (j < qt);
    if (more) {
      const int jn = (j + 1) * 64;
      kr0 = *(const uint4*)(kb + (size_t)(jn + r0) * 64 + cb0 / 2);
      kr1 = *(const uint4*)(kb + (size_t)(jn + r1) * 64 + cb1 / 2);
      vr0 = *(const uint4*)(vb + (size_t)r0 * TT + jn + cb0 / 2);
      vr1 = *(const uint4*)(vb + (size_t)r1 * TT + jn + cb1 / 2);
    }
    f32x4 s4[4] = {};
    __builtin_amdgcn_s_setprio(1);
#pragma unroll
    for (int kk = 0; kk < 2; ++kk) {
      const int cbyte = kk * 64 + lhi * 16;
#pragma unroll
      for (int nt = 0; nt < 4; ++nt) {
        const int krow = nt * 16 + l15;
        const bf16x8 kf = *(const bf16x8*)((char*)Ks + krow * 128 + (cbyte ^ ((krow & 7) << 4)));
        s4[nt] = mfma16(qf[kk], kf, s4[nt]);
      }
    }
    __builtin_amdgcn_s_setprio(0);
    const bool diag = (j == qt);
    float alpha[4];
#pragma unroll
    for (int r = 0; r < 4; ++r) {
      const int qg = qt * 64 + wid * 16 + (lhi << 2) + r;
      float mx = -INFINITY;
#pragma unroll
      for (int nt = 0; nt < 4; ++nt) {
        float v = s4[nt][r] * 0.125f;
        if (diag && (j * 64 + nt * 16 + l15) > qg) v = -INFINITY;
        s4[nt][r] = v;
        mx = fmaxf(mx, v);
      }
#pragma unroll
      for (int m = 1; m < 16; m <<= 1) mx = fmaxf(mx, __shfl_xor(mx, m, 16));
      const float mnew = fmaxf(mrun[r], mx);
      alpha[r] = __expf(mrun[r] - mnew);
      float ps = 0.f;
#pragma unroll
      for (int nt = 0; nt < 4; ++nt) {
        const float pp = __expf(s4[nt][r] - mnew);
        s4[nt][r] = pp;
        ps += pp;
      }
#pragma unroll
      for (int m = 1; m < 16; m <<= 1) ps += __shfl_xor(ps, m, 16);
      lrun[r] = lrun[r] * alpha[r] + ps;
      mrun[r] = mnew;
    }
#pragma unroll
    for (int dt = 0; dt < 4; ++dt)
#pragma unroll
      for (int r = 0; r < 4; ++r) oacc[dt][r] *= alpha[r];
#pragma unroll
    for (int r = 0; r < 4; ++r) {
      const int prow = (lhi << 2) + r;
      const int swp = (prow & 7) << 4;
#pragma unroll
      for (int nt = 0; nt < 4; ++nt) {
        const int cb = (nt * 16 + l15) * 2;
        *(uint16_t*)(pb + prow * 128 + (cb ^ swp)) = f2b(s4[nt][r]);
      }
    }
    __builtin_amdgcn_s_setprio(1);
#pragma unroll
    for (int kk = 0; kk < 2; ++kk) {
      const int cbyte = kk * 64 + lhi * 16;
      const bf16x8 pf = *(const bf16x8*)(pb + l15 * 128 + (cbyte ^ ((l15 & 7) << 4)));
#pragma unroll
      for (int dt = 0; dt < 4; ++dt) {
        const int vrow = dt * 16 + l15;
        const bf16x8 vf = *(const bf16x8*)((char*)Vs + vrow * 128 + (cbyte ^ ((vrow & 7) << 4)));
        oacc[dt] = mfma16(pf, vf, oacc[dt]);
      }
    }
    __builtin_amdgcn_s_setprio(0);
    __syncthreads();
    if (more) {
      *(uint4*)((char*)Ks + ph0) = kr0;
      *(uint4*)((char*)Ks + ph1) = kr1;
      *(uint4*)((char*)Vs + ph0) = vr0;
      *(uint4*)((char*)Vs + ph1) = vr1;
    }
    __syncthreads();
  }
#pragma unroll
  for (int dt = 0; dt < 4; ++dt) {
#pragma unroll
    for (int r = 0; r < 4; ++r) {
      const int q = qt * 64 + wid * 16 + (lhi << 2) + r;
      const float v = oacc[dt][r] / lrun[r];
      ao[(size_t)((bh / HH) * TT + q) * CC + (bh % HH) * HDIM + dt * 16 + l15] = f2b(v);
    }
  }
}

extern "C" void kernel_launch(void* const* d_in, const int* in_sizes, int n_in,
                              void* d_out, int out_size, void* d_ws, size_t ws_size,
                              hipStream_t stream) {
  (void)in_sizes; (void)n_in; (void)out_size;
  const int*   idx  = (const int*)d_in[0];
  const float* tok  = (const float*)d_in[1];
  const float* pos  = (const float*)d_in[2];
  const float* Wqkv = (const float*)d_in[3];
  const float* Wpro = (const float*)d_in[4];
  const float* W1   = (const float*)d_in[5];
  const float* b1   = (const float*)d_in[6];
  const float* W2   = (const float*)d_in[7];
  const float* b2   = (const float*)d_in[8];
  const float* g1   = (const float*)d_in[9];
  const float* be1  = (const float*)d_in[10];
  const float* g2   = (const float*)d_in[11];
  const float* be2  = (const float*)d_in[12];
  const float* gf   = (const float*)d_in[13];
  const float* bfb  = (const float*)d_in[14];
  float* out = (float*)d_out;

  char* p = (char*)d_ws;
  float* x = (float*)p;            p += (size_t)MM * CC * 4;
  uint16_t* act = (uint16_t*)p;    p += (size_t)MM * CC * 2;
  uint16_t* big = (uint16_t*)p;    p += (size_t)MM * DFF * 2;
  uint16_t* wq = (uint16_t*)p;     p += (size_t)CC * 3 * CC * 2;
  uint16_t* wp = (uint16_t*)p;     p += (size_t)CC * CC * 2;
  uint16_t* w1 = (uint16_t*)p;     p += (size_t)CC * DFF * 2;
  uint16_t* w2 = (uint16_t*)p;     p += (size_t)DFF * CC * 2;
  uint16_t* tokb = (uint16_t*)p;   p += (size_t)VV * CC * 2;
  float* part = (float*)p;         p += (size_t)2 * MM * CC * 4;   // split-K partials
  const bool roomy = ws_size >= (size_t)(p - (char*)d_ws);

  cvt4_k<<<dim3((VV * CC / 4 + 255) / 256), 256, 0, stream>>>(tok, tokb, VV * CC / 4);
  embed_k<<<dim3(MM * (CC / 4) / 256), 256, 0, stream>>>(idx, tok, pos, x);
  ln_k<<<dim3(MM / 4), 256, 0, stream>>>(x, g1, be1, act);   // LN1 for layer 0
  for (int l = 0; l < LNUM; ++l) {
    tconv_k<<<dim3(CC / 32, 3 * CC / 32), 256, 0, stream>>>(Wqkv + (size_t)l * CC * 3 * CC, wq, CC, 3 * CC);
    tconv_k<<<dim3(CC / 32, CC / 32), 256, 0, stream>>>(Wpro + (size_t)l * CC * CC, wp, CC, CC);
    tconv_k<<<dim3(CC / 32, DFF / 32), 256, 0, stream>>>(W1 + (size_t)l * CC * DFF, w1, CC, DFF);
    tconv_k<<<dim3(DFF / 32, CC / 32), 256, 0, stream>>>(W2 + (size_t)l * DFF * CC, w2, DFF, CC);
    // QKV: 32x9 = 288 blocks, nkt=12
    g256_k<5><<<dim3((MM / 256) * (3 * CC / 256)), 512, 0, stream>>>(
        act, wq, 3 * CC, CC, 3 * CC / 256, 1, nullptr, nullptr, big, nullptr);
    attn_k<<<dim3((TT / 64) * BB * HH), 256, 0, stream>>>(big, act);
    // proj: 32x3 = 96 blocks (single partial round), resid RMW
    g256_k<3><<<dim3((MM / 256) * (CC / 256)), 512, 0, stream>>>(
        act, wp, CC, CC, CC / 256, 1, nullptr, x, nullptr, nullptr);
    ln_k<<<dim3(MM / 4), 256, 0, stream>>>(x, g2 + (size_t)l * CC, be2 + (size_t)l * CC, act);
    // W1 + GELU: 32x12 = 384 blocks, nkt=12
    g256_k<2><<<dim3((MM / 256) * (DFF / 256)), 512, 0, stream>>>(
        act, w1, DFF, CC, DFF / 256, 1, b1 + (size_t)l * DFF, nullptr, big, nullptr);
    const float* ng = (l + 1 < LNUM) ? g1 + (size_t)(l + 1) * CC : gf;
    const float* nb = (l + 1 < LNUM) ? be1 + (size_t)(l + 1) * CC : bfb;
    if (roomy) {
      // W2: split-K=2 partials (32x3x2 = 192 blocks, nkt=24) -> lnr
      g256_k<7><<<dim3((MM / 256) * (CC / 256) * 2), 512, 0, stream>>>(
          big, w2, CC, DFF, CC / 256, 2, b2 + (size_t)l * CC, nullptr, nullptr, part);
      lnr_k<<<dim3(MM / 4), 256, 0, stream>>>(x, part, part + (size_t)MM * CC, ng, nb, act);
    } else {
      gemm_k<4><<<dim3(MM / 128, CC / 128), 256, 0, stream>>>(big, w2, CC, DFF, b2 + (size_t)l * CC, x, nullptr, nullptr);
      ln_k<<<dim3(MM / 4), 256, 0, stream>>>(x, ng, nb, act);
    }
  }
  gemm_k<1><<<dim3(MM / 128, VV / 128), 256, 0, stream>>>(act, tokb, VV, CC, nullptr, nullptr, nullptr, out);
}

// Round 9
// 1764.586 us; speedup vs baseline: 1.1451x; 1.1451x over previous
//
#include <hip/hip_runtime.h>
#include <hip/hip_bf16.h>
#include <stdint.h>

#define LNUM 6
#define BB 8
#define TT 1024
#define CC 768
#define HH 12
#define HDIM 64
#define DFF 3072
#define VV 512
#define MM (BB*TT)
#define QKREG ((size_t)BB*HH*TT*64)

typedef __bf16 bf16x8 __attribute__((ext_vector_type(8)));
typedef float f32x4 __attribute__((ext_vector_type(4)));

__device__ __forceinline__ uint16_t f2b(float f) {
  uint32_t u = __float_as_uint(f);
  u += 0x7FFFu + ((u >> 16) & 1u);
  return (uint16_t)(u >> 16);
}

__device__ __forceinline__ void gld16(const uint16_t* g, uint16_t* l) {
  __builtin_amdgcn_global_load_lds(
      (const __attribute__((address_space(1))) uint32_t*)g,
      (__attribute__((address_space(3))) uint32_t*)l, 16, 0, 0);
}

__device__ __forceinline__ f32x4 mfma16(bf16x8 a, bf16x8 b, f32x4 c) {
  return __builtin_amdgcn_mfma_f32_16x16x32_bf16(a, b, c, 0, 0, 0);
}

// ---------------- convert f32 -> bf16 ----------------
__global__ __launch_bounds__(256) void cvt4_k(const float* __restrict__ in,
                                              uint16_t* __restrict__ out, int n4) {
  const int gid = blockIdx.x * 256 + threadIdx.x;
  if (gid >= n4) return;
  const float4 v = ((const float4*)in)[gid];
  ushort4 w; w.x = f2b(v.x); w.y = f2b(v.y); w.z = f2b(v.z); w.w = f2b(v.w);
  ((ushort4*)out)[gid] = w;
}

// ---------------- embedding ----------------
__global__ __launch_bounds__(256) void embed_k(const int* __restrict__ idx,
                                               const float* __restrict__ tok,
                                               const float* __restrict__ pos,
                                               float* __restrict__ x) {
  const int gid = blockIdx.x * 256 + threadIdx.x;
  const int row = gid / (CC / 4), c4 = gid % (CC / 4);
  const int t = row & (TT - 1);
  const int tkn = idx[row];
  const float4 a = ((const float4*)(tok + (size_t)tkn * CC))[c4];
  const float4 q = ((const float4*)(pos + (size_t)t * CC))[c4];
  ((float4*)(x + (size_t)row * CC))[c4] =
      make_float4(a.x + q.x, a.y + q.y, a.z + q.z, a.w + q.w);
}

// ---------------- layernorm: fp32 in -> bf16 out ----------------
__global__ __launch_bounds__(256) void ln_k(const float* __restrict__ x,
                                            const float* __restrict__ gamma,
                                            const float* __restrict__ beta,
                                            uint16_t* __restrict__ o) {
  const int lane = threadIdx.x & 63, wid = threadIdx.x >> 6;
  const int row = blockIdx.x * 4 + wid;
  const float4* xr = (const float4*)(x + (size_t)row * CC);
  float4 v[3]; float s = 0.f, sq = 0.f;
#pragma unroll
  for (int i = 0; i < 3; ++i) {
    v[i] = xr[lane + i * 64];
    s += v[i].x + v[i].y + v[i].z + v[i].w;
    sq += v[i].x * v[i].x + v[i].y * v[i].y + v[i].z * v[i].z + v[i].w * v[i].w;
  }
#pragma unroll
  for (int m = 1; m < 64; m <<= 1) { s += __shfl_xor(s, m, 64); sq += __shfl_xor(sq, m, 64); }
  const float mu = s * (1.f / 768.f);
  const float rstd = rsqrtf(sq * (1.f / 768.f) - mu * mu + 1e-5f);
  ushort4* orow = (ushort4*)(o + (size_t)row * CC);
#pragma unroll
  for (int i = 0; i < 3; ++i) {
    const int c4 = lane + i * 64;
    const float4 gg = ((const float4*)gamma)[c4];
    const float4 bb = ((const float4*)beta)[c4];
    ushort4 w;
    w.x = f2b((v[i].x - mu) * rstd * gg.x + bb.x);
    w.y = f2b((v[i].y - mu) * rstd * gg.y + bb.y);
    w.z = f2b((v[i].z - mu) * rstd * gg.z + bb.z);
    w.w = f2b((v[i].w - mu) * rstd * gg.w + bb.w);
    orow[c4] = w;
  }
}

// ------- layernorm + partial-sum reduce: x += p0+p1; o = LN(x) -------
__global__ __launch_bounds__(256) void lnr_k(float* __restrict__ x,
                                             const float* __restrict__ p0,
                                             const float* __restrict__ p1,
                                             const float* __restrict__ gamma,
                                             const float* __restrict__ beta,
                                             uint16_t* __restrict__ o) {
  const int lane = threadIdx.x & 63, wid = threadIdx.x >> 6;
  const int row = blockIdx.x * 4 + wid;
  float4* xr = (float4*)(x + (size_t)row * CC);
  const float4* pr0 = (const float4*)(p0 + (size_t)row * CC);
  const float4* pr1 = (const float4*)(p1 + (size_t)row * CC);
  float4 v[3]; float s = 0.f, sq = 0.f;
#pragma unroll
  for (int i = 0; i < 3; ++i) {
    const int c4 = lane + i * 64;
    float4 a = xr[c4];
    const float4 q0 = pr0[c4];
    const float4 q1 = pr1[c4];
    a.x += q0.x + q1.x; a.y += q0.y + q1.y;
    a.z += q0.z + q1.z; a.w += q0.w + q1.w;
    xr[c4] = a;
    v[i] = a;
    s += a.x + a.y + a.z + a.w;
    sq += a.x * a.x + a.y * a.y + a.z * a.z + a.w * a.w;
  }
#pragma unroll
  for (int m = 1; m < 64; m <<= 1) { s += __shfl_xor(s, m, 64); sq += __shfl_xor(sq, m, 64); }
  const float mu = s * (1.f / 768.f);
  const float rstd = rsqrtf(sq * (1.f / 768.f) - mu * mu + 1e-5f);
  ushort4* orow = (ushort4*)(o + (size_t)row * CC);
#pragma unroll
  for (int i = 0; i < 3; ++i) {
    const int c4 = lane + i * 64;
    const float4 gg = ((const float4*)gamma)[c4];
    const float4 bb = ((const float4*)beta)[c4];
    ushort4 w;
    w.x = f2b((v[i].x - mu) * rstd * gg.x + bb.x);
    w.y = f2b((v[i].y - mu) * rstd * gg.y + bb.y);
    w.z = f2b((v[i].z - mu) * rstd * gg.z + bb.z);
    w.w = f2b((v[i].w - mu) * rstd * gg.w + bb.w);
    orow[c4] = w;
  }
}

// ------- all-weights transpose+convert (6 layers x 4 matrices, one launch) -------
// per-layer tiles: qkv 24x72=1728, proj 24x24=576, w1 24x96=2304, w2 96x24=2304
__global__ __launch_bounds__(256) void tca_k(const float* __restrict__ Wq,
                                             const float* __restrict__ Wp,
                                             const float* __restrict__ W1p,
                                             const float* __restrict__ W2p,
                                             uint16_t* __restrict__ dq,
                                             uint16_t* __restrict__ dp,
                                             uint16_t* __restrict__ d1,
                                             uint16_t* __restrict__ d2) {
  __shared__ float tile[32][33];
  const int b = blockIdx.x;
  const int l = b / 6912;
  int r = b - l * 6912;
  const float* src; uint16_t* dst; int K, N, kt, nt;
  if (r < 1728) {
    K = CC; N = 3 * CC;
    src = Wq + (size_t)l * CC * 3 * CC; dst = dq + (size_t)l * CC * 3 * CC;
    kt = r / 72; nt = r % 72;
  } else if (r < 2304) {
    r -= 1728; K = CC; N = CC;
    src = Wp + (size_t)l * CC * CC; dst = dp + (size_t)l * CC * CC;
    kt = r / 24; nt = r % 24;
  } else if (r < 4608) {
    r -= 2304; K = CC; N = DFF;
    src = W1p + (size_t)l * CC * DFF; dst = d1 + (size_t)l * CC * DFF;
    kt = r / 96; nt = r % 96;
  } else {
    r -= 4608; K = DFF; N = CC;
    src = W2p + (size_t)l * DFF * CC; dst = d2 + (size_t)l * DFF * CC;
    kt = r / 24; nt = r % 24;
  }
  const int tx = threadIdx.x & 31, ty = threadIdx.x >> 5;
  const int kb = kt * 32, nb = nt * 32;
#pragma unroll
  for (int i = 0; i < 32; i += 8)
    tile[ty + i][tx] = src[(size_t)(kb + ty + i) * N + nb + tx];
  __syncthreads();
#pragma unroll
  for (int i = 0; i < 32; i += 8)
    dst[(size_t)(nb + ty + i) * K + kb + tx] = f2b(tile[tx][ty + i]);
}

// ---------------- 128x128 GEMM (m97 structure, 16KB LDS, multi-block TLP) ----------------
// split-K via gridDim.z / blockIdx.z.
// EPI: 1 = f32 store; 2 = bias+GELU -> bf16; 5 = qkv split; 7 = f32 partials (+bias kp0)
template <int EPI>
__global__ __launch_bounds__(256) void gemm_k(const uint16_t* __restrict__ A,
                                              const uint16_t* __restrict__ Bt,
                                              int N, int K,
                                              const float* __restrict__ bias,
                                              uint16_t* __restrict__ outb,
                                              float* __restrict__ outf) {
  __shared__ __align__(16) uint16_t As[128 * 32];
  __shared__ __align__(16) uint16_t Bs[128 * 32];
  const int lane = threadIdx.x & 63, wid = threadIdx.x >> 6;
  const int wm = wid >> 1, wn = wid & 1;
  const int bm = blockIdx.x * 128, bn = blockIdx.y * 128;
  const int kp = blockIdx.z;
  const int Ksub = K / (int)gridDim.z;
  const int k0b = kp * Ksub;
  const int rsub = lane >> 2, csub = (lane & 3) * 8;
  f32x4 acc[4][4] = {};
  for (int k0 = k0b; k0 < k0b + Ksub; k0 += 32) {
#pragma unroll
    for (int q = 0; q < 2; ++q) {
      const int ch = wid * 2 + q;
      gld16(A + (size_t)(bm + ch * 16 + rsub) * K + k0 + csub, &As[ch * 512]);
      gld16(Bt + (size_t)(bn + ch * 16 + rsub) * K + k0 + csub, &Bs[ch * 512]);
    }
    __syncthreads();
    bf16x8 a[4], b[4];
#pragma unroll
    for (int i = 0; i < 4; ++i) {
      a[i] = *(const bf16x8*)&As[(wm * 64 + i * 16 + (lane & 15)) * 32 + (lane >> 4) * 8];
      b[i] = *(const bf16x8*)&Bs[(wn * 64 + i * 16 + (lane & 15)) * 32 + (lane >> 4) * 8];
    }
#pragma unroll
    for (int i = 0; i < 4; ++i)
#pragma unroll
      for (int j = 0; j < 4; ++j)
        acc[i][j] = mfma16(a[i], b[j], acc[i][j]);
    __syncthreads();
  }
#pragma unroll
  for (int i = 0; i < 4; ++i) {
    const int m0 = bm + wm * 64 + i * 16 + ((lane >> 4) << 2);
#pragma unroll
    for (int j = 0; j < 4; ++j) {
      const int n = bn + wn * 64 + j * 16 + (lane & 15);
      if constexpr (EPI == 5) {
        const int sec = n / CC;
        const int rn = n - sec * CC;
        const int hh = rn >> 6, d = rn & 63;
        const int b = m0 >> 10, t0 = m0 & 1023;
        if (sec == 2) {
          ushort4 w;
          w.x = f2b(acc[i][j][0]); w.y = f2b(acc[i][j][1]);
          w.z = f2b(acc[i][j][2]); w.w = f2b(acc[i][j][3]);
          *(ushort4*)(outb + 2 * QKREG + ((size_t)(b * HH + hh) * 64 + d) * TT + t0) = w;
        } else {
          uint16_t* dst = outb + (size_t)sec * QKREG + ((size_t)(b * HH + hh) * TT + t0) * 64 + d;
#pragma unroll
          for (int rr = 0; rr < 4; ++rr) dst[(size_t)rr * 64] = f2b(acc[i][j][rr]);
        }
      } else if constexpr (EPI == 7) {
        float* pdst = outf + (size_t)kp * ((size_t)MM * N);
        const float bb = (kp == 0 && bias) ? bias[n] : 0.f;
#pragma unroll
        for (int rr = 0; rr < 4; ++rr)
          pdst[(size_t)(m0 + rr) * N + n] = acc[i][j][rr] + bb;
      } else {
#pragma unroll
        for (int rr = 0; rr < 4; ++rr) {
          const size_t o = (size_t)(m0 + rr) * N + n;
          const float v = acc[i][j][rr];
          if constexpr (EPI == 1) {
            outf[o] = v;
          } else if constexpr (EPI == 2) {
            float t = v + bias[n];
            t = 0.5f * t * (1.0f + erff(t * 0.70710678118654752f));
            outb[o] = f2b(t);
          }
        }
      }
    }
  }
}

// ---------------- fused causal flash attention ----------------
__global__ __launch_bounds__(256) void attn_k(const uint16_t* __restrict__ qkvh,
                                              uint16_t* __restrict__ ao) {
  __shared__ __align__(16) uint16_t Ks[64 * 64], Vs[64 * 64];
  __shared__ __align__(16) uint16_t Ps[4][16 * 64];
  const int tid = threadIdx.x, lane = tid & 63, wid = tid >> 6;
  const int qt = (TT / 64 - 1) - blockIdx.x / (BB * HH);
  const int bh = blockIdx.x % (BB * HH);
  const uint16_t* qb = qkvh + (size_t)bh * (TT * 64);
  const uint16_t* kb = qkvh + QKREG + (size_t)bh * (TT * 64);
  const uint16_t* vb = qkvh + 2 * QKREG + (size_t)bh * ((size_t)64 * TT);
  const int l15 = lane & 15, lhi = lane >> 4;
  bf16x8 qf[2];
  {
    const uint16_t* qr = qb + (size_t)(qt * 64 + wid * 16 + l15) * 64 + lhi * 8;
    qf[0] = *(const bf16x8*)qr;
    qf[1] = *(const bf16x8*)(qr + 32);
  }
  const int c0 = tid, c1 = tid + 256;
  const int r0 = c0 >> 3, r1 = c1 >> 3;
  const int cb0 = (c0 & 7) * 16, cb1 = (c1 & 7) * 16;
  const int ph0 = r0 * 128 + (cb0 ^ ((r0 & 7) << 4));
  const int ph1 = r1 * 128 + (cb1 ^ ((r1 & 7) << 4));

  uint4 kr0, kr1, vr0, vr1;
  kr0 = *(const uint4*)(kb + (size_t)r0 * 64 + cb0 / 2);
  kr1 = *(const uint4*)(kb + (size_t)r1 * 64 + cb1 / 2);
  vr0 = *(const uint4*)(vb + (size_t)r0 * TT + cb0 / 2);
  vr1 = *(const uint4*)(vb + (size_t)r1 * TT + cb1 / 2);
  *(uint4*)((char*)Ks + ph0) = kr0;
  *(uint4*)((char*)Ks + ph1) = kr1;
  *(uint4*)((char*)Vs + ph0) = vr0;
  *(uint4*)((char*)Vs + ph1) = vr1;
  __syncthreads();

  f32x4 oacc[4] = {};
  float mrun[4] = {-INFINITY, -INFINITY, -INFINITY, -INFINITY};
  float lrun[4] = {0.f, 0.f, 0.f, 0.f};
  char* pb = (char*)Ps[wid];

  for (int j = 0; j <= qt; ++j) {
    const bool more = (j < qt);
    if (more) {
      const int jn = (j + 1) * 64;
      kr0 = *(const uint4*)(kb + (size_t)(jn + r0) * 64 + cb0 / 2);
      kr1 = *(const uint4*)(kb + (size_t)(jn + r1) * 64 + cb1 / 2);
      vr0 = *(const uint4*)(vb + (size_t)r0 * TT + jn + cb0 / 2);
      vr1 = *(const uint4*)(vb + (size_t)r1 * TT + jn + cb1 / 2);
    }
    f32x4 s4[4] = {};
    __builtin_amdgcn_s_setprio(1);
#pragma unroll
    for (int kk = 0; kk < 2; ++kk) {
      const int cbyte = kk * 64 + lhi * 16;
#pragma unroll
      for (int nt = 0; nt < 4; ++nt) {
        const int krow = nt * 16 + l15;
        const bf16x8 kf = *(const bf16x8*)((char*)Ks + krow * 128 + (cbyte ^ ((krow & 7) << 4)));
        s4[nt] = mfma16(qf[kk], kf, s4[nt]);
      }
    }
    __builtin_amdgcn_s_setprio(0);
    const bool diag = (j == qt);
    float alpha[4];
#pragma unroll
    for (int r = 0; r < 4; ++r) {
      const int qg = qt * 64 + wid * 16 + (lhi << 2) + r;
      float mx = -INFINITY;
#pragma unroll
      for (int nt = 0; nt < 4; ++nt) {
        float v = s4[nt][r] * 0.125f;
        if (diag && (j * 64 + nt * 16 + l15) > qg) v = -INFINITY;
        s4[nt][r] = v;
        mx = fmaxf(mx, v);
      }
#pragma unroll
      for (int m = 1; m < 16; m <<= 1) mx = fmaxf(mx, __shfl_xor(mx, m, 16));
      const float mnew = fmaxf(mrun[r], mx);
      alpha[r] = __expf(mrun[r] - mnew);
      float ps = 0.f;
#pragma unroll
      for (int nt = 0; nt < 4; ++nt) {
        const float pp = __expf(s4[nt][r] - mnew);
        s4[nt][r] = pp;
        ps += pp;
      }
#pragma unroll
      for (int m = 1; m < 16; m <<= 1) ps += __shfl_xor(ps, m, 16);
      lrun[r] = lrun[r] * alpha[r] + ps;
      mrun[r] = mnew;
    }
#pragma unroll
    for (int dt = 0; dt < 4; ++dt)
#pragma unroll
      for (int r = 0; r < 4; ++r) oacc[dt][r] *= alpha[r];
#pragma unroll
    for (int r = 0; r < 4; ++r) {
      const int prow = (lhi << 2) + r;
      const int swp = (prow & 7) << 4;
#pragma unroll
      for (int nt = 0; nt < 4; ++nt) {
        const int cb = (nt * 16 + l15) * 2;
        *(uint16_t*)(pb + prow * 128 + (cb ^ swp)) = f2b(s4[nt][r]);
      }
    }
    __builtin_amdgcn_s_setprio(1);
#pragma unroll
    for (int kk = 0; kk < 2; ++kk) {
      const int cbyte = kk * 64 + lhi * 16;
      const bf16x8 pf = *(const bf16x8*)(pb + l15 * 128 + (cbyte ^ ((l15 & 7) << 4)));
#pragma unroll
      for (int dt = 0; dt < 4; ++dt) {
        const int vrow = dt * 16 + l15;
        const bf16x8 vf = *(const bf16x8*)((char*)Vs + vrow * 128 + (cbyte ^ ((vrow & 7) << 4)));
        oacc[dt] = mfma16(pf, vf, oacc[dt]);
      }
    }
    __builtin_amdgcn_s_setprio(0);
    __syncthreads();
    if (more) {
      *(uint4*)((char*)Ks + ph0) = kr0;
      *(uint4*)((char*)Ks + ph1) = kr1;
      *(uint4*)((char*)Vs + ph0) = vr0;
      *(uint4*)((char*)Vs + ph1) = vr1;
    }
    __syncthreads();
  }
#pragma unroll
  for (int dt = 0; dt < 4; ++dt) {
#pragma unroll
    for (int r = 0; r < 4; ++r) {
      const int q = qt * 64 + wid * 16 + (lhi << 2) + r;
      const float v = oacc[dt][r] / lrun[r];
      ao[(size_t)((bh / HH) * TT + q) * CC + (bh % HH) * HDIM + dt * 16 + l15] = f2b(v);
    }
  }
}

extern "C" void kernel_launch(void* const* d_in, const int* in_sizes, int n_in,
                              void* d_out, int out_size, void* d_ws, size_t ws_size,
                              hipStream_t stream) {
  (void)in_sizes; (void)n_in; (void)out_size;
  const int*   idx  = (const int*)d_in[0];
  const float* tok  = (const float*)d_in[1];
  const float* pos  = (const float*)d_in[2];
  const float* Wqkv = (const float*)d_in[3];
  const float* Wpro = (const float*)d_in[4];
  const float* W1   = (const float*)d_in[5];
  const float* b1   = (const float*)d_in[6];
  const float* W2   = (const float*)d_in[7];
  const float* b2   = (const float*)d_in[8];
  const float* g1   = (const float*)d_in[9];
  const float* be1  = (const float*)d_in[10];
  const float* g2   = (const float*)d_in[11];
  const float* be2  = (const float*)d_in[12];
  const float* gf   = (const float*)d_in[13];
  const float* bfb  = (const float*)d_in[14];
  float* out = (float*)d_out;

  const size_t QS = (size_t)CC * 3 * CC;   // qkv slice elems
  const size_t PS = (size_t)CC * CC;
  const size_t S1 = (size_t)CC * DFF;
  const size_t S2 = (size_t)DFF * CC;

  char* p = (char*)d_ws;
  float* x = (float*)p;            p += (size_t)MM * CC * 4;
  uint16_t* act = (uint16_t*)p;    p += (size_t)MM * CC * 2;
  uint16_t* big = (uint16_t*)p;    p += (size_t)MM * DFF * 2;
  uint16_t* tokb = (uint16_t*)p;   p += (size_t)VV * CC * 2;
  float* part = (float*)p;         p += (size_t)2 * MM * CC * 4;
  char* pbase = p;
  // 6-layer weight region
  uint16_t* wqA = (uint16_t*)p;    p += QS * LNUM * 2;
  uint16_t* wpA = (uint16_t*)p;    p += PS * LNUM * 2;
  uint16_t* w1A = (uint16_t*)p;    p += S1 * LNUM * 2;
  uint16_t* w2A = (uint16_t*)p;    p += S2 * LNUM * 2;
  const bool roomy2 = ws_size >= (size_t)(p - (char*)d_ws);
  if (!roomy2) {  // compact: single-layer slices
    p = pbase;
    wqA = (uint16_t*)p; p += QS * 2;
    wpA = (uint16_t*)p; p += PS * 2;
    w1A = (uint16_t*)p; p += S1 * 2;
    w2A = (uint16_t*)p; p += S2 * 2;
  }

  cvt4_k<<<dim3((VV * CC / 4 + 255) / 256), 256, 0, stream>>>(tok, tokb, VV * CC / 4);
  embed_k<<<dim3(MM * (CC / 4) / 256), 256, 0, stream>>>(idx, tok, pos, x);
  ln_k<<<dim3(MM / 4), 256, 0, stream>>>(x, g1, be1, act);   // LN1 for layer 0
  if (roomy2)
    tca_k<<<dim3(LNUM * 6912), 256, 0, stream>>>(Wqkv, Wpro, W1, W2, wqA, wpA, w1A, w2A);

  for (int l = 0; l < LNUM; ++l) {
    if (!roomy2)
      tca_k<<<dim3(6912), 256, 0, stream>>>(Wqkv + (size_t)l * QS, Wpro + (size_t)l * PS,
                                            W1 + (size_t)l * S1, W2 + (size_t)l * S2,
                                            wqA, wpA, w1A, w2A);
    const size_t lw = roomy2 ? (size_t)l : 0;
    // QKV: grid 64x18 = 1152 blocks (4.5/CU)
    gemm_k<5><<<dim3(MM / 128, 3 * CC / 128, 1), 256, 0, stream>>>(
        act, wqA + lw * QS, 3 * CC, CC, nullptr, big, nullptr);
    attn_k<<<dim3((TT / 64) * BB * HH), 256, 0, stream>>>(big, act);
    // proj: split-K2 -> 64x6x2 = 768 blocks (3/CU), f32 partials (no bias)
    gemm_k<7><<<dim3(MM / 128, CC / 128, 2), 256, 0, stream>>>(
        act, wpA + lw * PS, CC, CC, nullptr, nullptr, part);
    lnr_k<<<dim3(MM / 4), 256, 0, stream>>>(x, part, part + (size_t)MM * CC,
                                            g2 + (size_t)l * CC, be2 + (size_t)l * CC, act);
    // W1 + GELU: grid 64x24 = 1536 blocks (6/CU)
    gemm_k<2><<<dim3(MM / 128, DFF / 128, 1), 256, 0, stream>>>(
        act, w1A + lw * S1, DFF, CC, b1 + (size_t)l * DFF, big, nullptr);
    // W2: split-K2 -> 64x6x2 = 768 blocks, f32 partials (+bias on kp0)
    const float* ng = (l + 1 < LNUM) ? g1 + (size_t)(l + 1) * CC : gf;
    const float* nb = (l + 1 < LNUM) ? be1 + (size_t)(l + 1) * CC : bfb;
    gemm_k<7><<<dim3(MM / 128, CC / 128, 2), 256, 0, stream>>>(
        big, w2A + lw * S2, CC, DFF, b2 + (size_t)l * CC, nullptr, part);
    lnr_k<<<dim3(MM / 4), 256, 0, stream>>>(x, part, part + (size_t)MM * CC, ng, nb, act);
  }
  gemm_k<1><<<dim3(MM / 128, VV / 128, 1), 256, 0, stream>>>(
      act, tokb, VV, CC, nullptr, nullptr, out);
}